// Round 17
// baseline (257.191 us; speedup 1.0000x reference)
//
#include <hip/hip_runtime.h>
#include <hip/hip_bf16.h>
#include <math.h>

#define NH 32
#define NKV 8
#define HD 64
#define NSLOTS 11
#define TOPK 128
#define KBROW (NSLOTS * NH * HD)   // 22528
#define PADF (-3.3895313892515355e+38f)
#define C0F  (-0.24686007793152578f)   // -ln(128)+ln(100)
#define SCALE 0.125f
#define HCH 32                         // S-chunks for hierarchical column sum

typedef __attribute__((ext_vector_type(8))) __bf16 bf16x8;
typedef __attribute__((ext_vector_type(8))) unsigned short u16x8;
typedef __attribute__((ext_vector_type(4))) float f32x4;

#define GLDS16(gp, lp)                                                        \
  __builtin_amdgcn_global_load_lds(                                           \
      (__attribute__((address_space(1))) void*)(gp),                          \
      (__attribute__((address_space(3))) void*)(lp), 16, 0, 0)

__device__ __forceinline__ unsigned short f2bf(float f) {
  unsigned int u = __float_as_uint(f);
  u = (u + 0x7fffu + ((u >> 16) & 1u)) >> 16;
  return (unsigned short)u;
}

// byte offset into a 64-col bf16 tile (128 B/row) with XOR chunk swizzle
__device__ __forceinline__ int swz(int row, int chunk) {
  return row * 128 + ((chunk ^ (row & 7)) << 4);
}

// ---------------------------------------------------------------------------
// Merged: (a) fp32->bf16 of 5 weight sources into wall|wobf (flat copy),
// (b) hidden column-sum stage 1 + fused hidden f2bf.
// Blocks [0, nconv) do (a); blocks [nconv, nconv+512) do (b).
// ---------------------------------------------------------------------------
__global__ __launch_bounds__(256) void conv_hsum1(
    const float* __restrict__ s0, const float* __restrict__ s1,
    const float* __restrict__ s2, const float* __restrict__ s3,
    const float* __restrict__ s4,
    int n0, int n1, int n2, int n3, int n4_, int nconv,
    unsigned short* __restrict__ wout,
    const float* __restrict__ hidden, double* __restrict__ part,
    unsigned short* __restrict__ hbf, int B, int S, int H) {
  if ((int)blockIdx.x < nconv) {
    int i = blockIdx.x * 256 + threadIdx.x;
    int j = i;
    const float* src;
    if (j < n0) src = s0;
    else { j -= n0; if (j < n1) src = s1;
    else { j -= n1; if (j < n2) src = s2;
    else { j -= n2; if (j < n3) src = s3;
    else { j -= n3; if (j >= n4_) return; src = s4; }}}}
    float4 v = ((const float4*)src)[j];
    ushort4 o = {f2bf(v.x), f2bf(v.y), f2bf(v.z), f2bf(v.w)};
    ((ushort4*)wout)[i] = o;
  } else {
    int bid = blockIdx.x - nconv;
    const int nhb = H >> 8;
    int hb = bid % nhb;
    int ch = (bid / nhb) % HCH;
    int b  = bid / (nhb * HCH);
    int c  = hb * 256 + threadIdx.x;
    int rows = S / HCH;
    size_t base = ((size_t)b * S + (size_t)ch * rows) * H + c;
    const float* p = hidden + base;
    double acc = 0.0;
    for (int s = 0; s < rows; ++s) {
      float v = p[(size_t)s * H];
      acc += (double)v;
      hbf[base + (size_t)s * H] = f2bf(v);
    }
    part[((size_t)b * HCH + ch) * H + c] = acc;
  }
}

// ---------------------------------------------------------------------------
// bf16 MFMA GEMM, split-K=2, atomic accumulation into zero-initialized out.
// Deterministic: 2 contributions, (0+a)+b == (0+b)+a bit-exactly.
// ---------------------------------------------------------------------------
__global__ __launch_bounds__(256) void gemm_nt_splitk(
    const unsigned short* __restrict__ A, const unsigned short* __restrict__ B,
    float* __restrict__ out, int M, int N, int K) {
  __shared__ unsigned short ldsA[128 * 32];
  __shared__ unsigned short ldsB[128 * 32];
  const int t = threadIdx.x;
  const int l = t & 63, w = t >> 6;
  const int wr = w >> 1, wc = w & 1;
  const int lr = l & 15;
  const int kb = (l >> 4) * 16;
  const int bm = blockIdx.y * 128, bn = blockIdx.x * 128;
  const int k0base = blockIdx.z * (K >> 1);
  const int kend = k0base + (K >> 1);

  f32x4 acc[4][4] = {};

  for (int k0 = k0base; k0 < kend; k0 += 32) {
    __syncthreads();
#pragma unroll
    for (int it = 0; it < 2; ++it) {
      int s = it * 256 + t;
      int row = s >> 2, cs = (s & 3) * 8;
      GLDS16(A + (size_t)(bm + row) * K + k0 + cs,
             (char*)ldsA + (it * 4 + w) * 1024);
      GLDS16(B + (size_t)(bn + row) * K + k0 + cs,
             (char*)ldsB + (it * 4 + w) * 1024);
    }
    __syncthreads();

    bf16x8 a[4], b[4];
#pragma unroll
    for (int m = 0; m < 4; ++m)
      a[m] = *(const bf16x8*)((const char*)ldsA +
                              (wr * 64 + m * 16 + lr) * 64 + kb);
#pragma unroll
    for (int n = 0; n < 4; ++n)
      b[n] = *(const bf16x8*)((const char*)ldsB +
                              (wc * 64 + n * 16 + lr) * 64 + kb);
#pragma unroll
    for (int m = 0; m < 4; ++m)
#pragma unroll
      for (int n = 0; n < 4; ++n)
        acc[m][n] =
            __builtin_amdgcn_mfma_f32_16x16x32_bf16(a[m], b[n], acc[m][n], 0, 0, 0);
  }

#pragma unroll
  for (int m = 0; m < 4; ++m)
#pragma unroll
    for (int n = 0; n < 4; ++n) {
      int rbase = bm + wr * 64 + m * 16 + ((l >> 4) << 2);
      int cbase = bn + wc * 64 + n * 16 + lr;
#pragma unroll
      for (int j = 0; j < 4; ++j)
        unsafeAtomicAdd(&out[(size_t)(rbase + j) * N + cbase], acc[m][n][j]);
    }
}

// ---------------------------------------------------------------------------
// 16-wave 256x256 deep-pipelined projection GEMM + RoPE epilogue + direct
// V^T. (v6, unchanged from R16.)
// ---------------------------------------------------------------------------
__global__ __launch_bounds__(1024) void gemm_proj8(
    const unsigned short* __restrict__ A,      // hbf [M][K]
    const unsigned short* __restrict__ Wall,   // [5120][K]
    const float* __restrict__ cosb, const float* __restrict__ sinb,
    unsigned short* __restrict__ qbf, unsigned short* __restrict__ q2bf,
    unsigned short* __restrict__ kbf, unsigned short* __restrict__ vTb,
    int M, int K, int S) {
  __shared__ char lds[131072];  // 2 buffers x (A 32KB | B 32KB)
  const int t = threadIdx.x;
  const int w = t >> 6;                 // 0..15
  const int wm = w >> 2, wn = w & 3;    // 4M x 4N
  const int l = t & 63;
  const int li = l & 15, lg4 = l >> 4;
  const int bm = blockIdx.y * 256, bn = blockIdx.x * 256;
  const int NK = K >> 6;

  f32x4 acc[4][4] = {};

#define STAGE_UNIT(kt1, nb, u)                                                \
  {                                                                           \
    const int slice_ = (u) >> 1;                                              \
    const unsigned short* mat_ = ((u) & 1) ? Wall : A;                        \
    const int tb_ = ((u) & 1) ? bn : bm;                                      \
    char* base_ = lds + (nb) * 65536 + (((u) & 1) ? 32768 : 0) +              \
                  slice_ * 16384;                                             \
    int row_ = t >> 2, cc_ = t & 3;                                           \
    int chunk_ = cc_ ^ ((row_ >> 1) & 3);                                     \
    GLDS16(mat_ + (size_t)(tb_ + row_) * K + (kt1) * 64 + slice_ * 32 +       \
               chunk_ * 8,                                                    \
           base_ + w * 1024);                                                 \
  }

  STAGE_UNIT(0, 0, 0); STAGE_UNIT(0, 0, 1);
  STAGE_UNIT(0, 0, 2); STAGE_UNIT(0, 0, 3);
  asm volatile("s_waitcnt vmcnt(2)" ::: "memory");
  asm volatile("s_barrier" ::: "memory");

  for (int kt = 0; kt < NK; ++kt) {
    const int cur = kt & 1;
    const bool stg = (kt + 1 < NK);
    char* curA = lds + cur * 65536;
    char* curB = curA + 32768;
#pragma unroll
    for (int kk = 0; kk < 2; ++kk) {
      bf16x8 bfr[4], af[4];
#pragma unroll
      for (int n = 0; n < 4; ++n) {
        int row = wn * 64 + n * 16 + li;
        bfr[n] = *(const bf16x8*)(curB + kk * 16384 + row * 64 +
                                  ((lg4 ^ ((row >> 1) & 3)) << 4));
      }
#pragma unroll
      for (int mi = 0; mi < 4; ++mi) {
        int row = wm * 64 + mi * 16 + li;
        af[mi] = *(const bf16x8*)(curA + kk * 16384 + row * 64 +
                                  ((lg4 ^ ((row >> 1) & 3)) << 4));
      }
      if (stg) {
        STAGE_UNIT(kt + 1, cur ^ 1, kk * 2)
        STAGE_UNIT(kt + 1, cur ^ 1, kk * 2 + 1)
      }
#pragma unroll
      for (int mi = 0; mi < 4; ++mi)
#pragma unroll
        for (int n = 0; n < 4; ++n)
          acc[mi][n] = __builtin_amdgcn_mfma_f32_16x16x32_bf16(
              af[mi], bfr[n], acc[mi][n], 0, 0, 0);
      if (kk == 0) {
        if (kt == NK - 1) asm volatile("s_waitcnt vmcnt(0)" ::: "memory");
        else              asm volatile("s_waitcnt vmcnt(2)" ::: "memory");
        asm volatile("s_barrier" ::: "memory");
      } else {
        if (stg) {
          asm volatile("s_waitcnt vmcnt(2)" ::: "memory");
          asm volatile("s_barrier" ::: "memory");
        }
      }
    }
  }
#undef STAGE_UNIT

  const int seg = bn;  // block-uniform
#pragma unroll
  for (int m = 0; m < 4; ++m) {
    const int row0 = bm + wm * 64 + m * 16 + lg4 * 4;
    if (seg < 2048 || (seg >= 4096 && seg < 4608)) {
      const bool isq = seg < 2048;
#pragma unroll
      for (int j = 0; j < 4; ++j) {
        int row = row0 + j;
        const float* cr = cosb + (size_t)row * 64;
        const float* sr = sinb + (size_t)row * 64;
        float c0 = cr[li], c1 = cr[16 + li], c2 = cr[32 + li], c3 = cr[48 + li];
        float sa = sr[li], sb = sr[16 + li], sc_ = sr[32 + li], sd = sr[48 + li];
        float x0 = acc[m][0][j], x1 = acc[m][1][j];
        float x2 = acc[m][2][j], x3 = acc[m][3][j];
        float y0 = x0 * c0 - x2 * sa;
        float y1 = x1 * c1 - x3 * sb;
        float y2 = x2 * c2 + x0 * sc_;
        float y3 = x3 * c3 + x1 * sd;
        if (isq) {
          size_t ro = (size_t)row * 2048 + bn + wn * 64 + li;
          qbf[ro] = f2bf(y0); qbf[ro + 16] = f2bf(y1);
          qbf[ro + 32] = f2bf(y2); qbf[ro + 48] = f2bf(y3);
        } else {
          size_t ro = (size_t)row * 512 + (bn - 4096) + wn * 64 + li;
          kbf[ro] = f2bf(y0); kbf[ro + 16] = f2bf(y1);
          kbf[ro + 32] = f2bf(y2); kbf[ro + 48] = f2bf(y3);
        }
      }
    } else if (seg < 4096) {  // q2 -> bf16
#pragma unroll
      for (int n = 0; n < 4; ++n) {
        int col = bn - 2048 + wn * 64 + n * 16 + li;
#pragma unroll
        for (int j = 0; j < 4; ++j)
          q2bf[(size_t)(row0 + j) * 2048 + col] = f2bf(acc[m][n][j]);
      }
    } else {  // v -> vT bf16 direct (j=0..3 consecutive s)
      int b_ = row0 / S, s = row0 % S;
#pragma unroll
      for (int n = 0; n < 4; ++n) {
        int col = (bn - 4608) + wn * 64 + n * 16 + li;
        int gg = col >> 6, d = col & 63;
        ushort4 o = {f2bf(acc[m][n][0]), f2bf(acc[m][n][1]),
                     f2bf(acc[m][n][2]), f2bf(acc[m][n][3])};
        *(ushort4*)&vTb[(((size_t)b_ * NKV + gg) * 64 + d) * S + s] = o;
      }
    }
  }
}

// ---------------------------------------------------------------------------
// Merged: (a) KB key slice bf16 (blocks [0,256)), (b) padflag (blocks 256+).
// ---------------------------------------------------------------------------
__global__ __launch_bounds__(256) void kbkh_padflag(
    const float* __restrict__ kbk, unsigned short* __restrict__ kout,
    const float* __restrict__ mask, int* __restrict__ flags, int BS, int S) {
  if (blockIdx.x < 256) {
    int i = blockIdx.x * 256 + threadIdx.x;
    int j = i >> 9, c4 = (i & 511) * 4;
    float4 v = *(const float4*)&kbk[(size_t)j * KBROW + c4];
    ushort4 o = {f2bf(v.x), f2bf(v.y), f2bf(v.z), f2bf(v.w)};
    *(ushort4*)&kout[(size_t)j * 2048 + c4] = o;
  } else {
    int w = (((int)blockIdx.x - 256) * 256 + (int)threadIdx.x) >> 6;
    int lane = threadIdx.x & 63;
    if (w >= BS) return;
    const float* row = mask + (size_t)w * S;
    bool ok = true;
    for (int j = lane; j < S; j += 64) ok = ok && (row[j] < 0.f);
    int allv = __all(ok ? 1 : 0);
    if (lane == 0) flags[w] = allv;
  }
}

// ---------------------------------------------------------------------------
// Gathered + transposed KB values -> [B][NH][64][128] bf16.
// ---------------------------------------------------------------------------
__global__ __launch_bounds__(256) void kbvgt_kernel(
    const float* __restrict__ kbv, const int* __restrict__ topi,
    unsigned short* __restrict__ kbvgT, int B) {
  int h = blockIdx.x % NH, b = blockIdx.x / NH;
  __shared__ unsigned short gt[128][72];
  __shared__ int lidx[TOPK];
  int t = threadIdx.x;
  if (t < TOPK) lidx[t] = topi[b * TOPK + t];
  __syncthreads();
#pragma unroll
  for (int it = 0; it < 8; ++it) {
    int slot = it * 256 + t;
    int j = slot >> 4, d4 = (slot & 15) * 4;
    float4 v = *(const float4*)&kbv[(size_t)lidx[j] * KBROW + h * 64 + d4];
    gt[j][d4] = f2bf(v.x); gt[j][d4 + 1] = f2bf(v.y);
    gt[j][d4 + 2] = f2bf(v.z); gt[j][d4 + 3] = f2bf(v.w);
  }
  __syncthreads();
#pragma unroll
  for (int it = 0; it < 4; ++it) {
    int slot = it * 256 + t;
    int d = slot >> 4, j8 = (slot & 15) * 8;
    u16x8 o;
#pragma unroll
    for (int j = 0; j < 8; ++j) o[j] = gt[j8 + j][d];
    *(u16x8*)&kbvgT[(((size_t)b * NH + h) * 64 + d) * 128 + j8] = o;
  }
}

// ---------------------------------------------------------------------------
// Column-sum stage 2: Hsum[b][c] = sum_ch part[b][ch][c] (f64, fixed order).
// ---------------------------------------------------------------------------
__global__ void hsum2_kernel(const double* __restrict__ part,
                             float* __restrict__ Hsum, int B, int H) {
  int idx = blockIdx.x * blockDim.x + threadIdx.x;
  if (idx >= B * H) return;
  int b = idx / H, c = idx % H;
  const double* p = part + (size_t)b * HCH * H + c;
  double acc = 0.0;
#pragma unroll
  for (int ch = 0; ch < HCH; ++ch) acc += p[(size_t)ch * H];
  Hsum[idx] = (float)acc;
}

// ---------------------------------------------------------------------------
// Qs[b][c] = sum_k Hsum[b][k] * Wq2[c][k]  (fp32 inputs, f64 accum).
// ---------------------------------------------------------------------------
__global__ void qs_kernel(const float* __restrict__ Hsum,
                          const float* __restrict__ Wq2,
                          float* __restrict__ Qs, int B, int H) {
  int task = (blockIdx.x * blockDim.x + threadIdx.x) >> 6;
  int lane = threadIdx.x & 63;
  if (task >= B * NH * HD) return;
  int b = task / (NH * HD), c = task % (NH * HD);
  const float* hs = Hsum + (size_t)b * H;
  const float* wr = Wq2 + (size_t)c * H;
  double acc = 0.0;
  for (int k = lane; k < H; k += 64) acc += (double)hs[k] * (double)wr[k];
#pragma unroll
  for (int off = 32; off; off >>= 1) acc += __shfl_xor(acc, off);
  if (lane == 0) Qs[task] = (float)acc;
}

// ---------------------------------------------------------------------------
// scores[b][l] = 0.125 * dot(Qs[b,:], kb_keys[l, 0:2048]) (f64 acc)
// ---------------------------------------------------------------------------
__global__ void scores_kernel(const float* __restrict__ Qs,
                              const float* __restrict__ kbk,
                              float* __restrict__ scores, int B, int KBL) {
  int task = (blockIdx.x * blockDim.x + threadIdx.x) >> 6;
  int lane = threadIdx.x & 63;
  if (task >= B * KBL) return;
  int b = task / KBL, l = task % KBL;
  const float* kr = kbk + (size_t)l * KBROW;
  const float* qd = Qs + (size_t)b * NH * HD;
  double acc = 0.0;
  for (int c = lane; c < NH * HD; c += 64) acc += (double)qd[c] * (double)kr[c];
#pragma unroll
  for (int off = 32; off; off >>= 1) acc += __shfl_xor(acc, off);
  if (lane == 0) scores[task] = (float)(0.125 * acc);
}

// ---------------------------------------------------------------------------
// Top-K by rank-counting (stable descending == lax.top_k).
// ---------------------------------------------------------------------------
__global__ __launch_bounds__(256) void topk_kernel(
    const float* __restrict__ scores, int* __restrict__ top_idx, int KBL) {
  __shared__ float ls[512];
  int b = blockIdx.x, t = threadIdx.x;
  for (int i = t; i < KBL; i += 256) ls[i] = scores[(size_t)b * KBL + i];
  __syncthreads();
  for (int l = t; l < KBL; l += 256) {
    float sl = ls[l];
    int rank = 0;
    for (int j = 0; j < KBL; ++j) {
      float sj = ls[j];
      rank += (sj > sl || (sj == sl && j < l)) ? 1 : 0;
    }
    if (rank < TOPK) top_idx[b * TOPK + rank] = l;
  }
}

// ---------------------------------------------------------------------------
// Load one K/V chunk's staged data into registers (4 x bf16x8 per thread).
// ---------------------------------------------------------------------------
__device__ __forceinline__ void load_chunk(
    int ch, int t, int b, int h, int g, int S,
    const unsigned short* __restrict__ kbf, const unsigned short* __restrict__ vTb,
    const unsigned short* __restrict__ kbkh, const unsigned short* __restrict__ kbvgT,
    bf16x8* st) {
  bool iskb = ch < 2;
  int j0 = iskb ? ch * 64 : (ch - 2) * 64;
#pragma unroll
  for (int it = 0; it < 4; ++it) {
    int slot = it * 256 + t;
    int tile = slot >> 9, row = (slot >> 3) & 63, ck = slot & 7;
    const unsigned short* src;
    if (tile == 0)
      src = iskb ? kbkh + (size_t)(j0 + row) * 2048 + h * 64 + ck * 8
                 : kbf + (size_t)(b * S + j0 + row) * 512 + g * 64 + ck * 8;
    else
      src = iskb ? kbvgT + (((size_t)b * NH + h) * 64 + row) * 128 + j0 + ck * 8
                 : vTb + (((size_t)b * NKV + g) * 64 + row) * (size_t)S + j0 + ck * 8;
    st[it] = *(const bf16x8*)src;
  }
}

// ---------------------------------------------------------------------------
// One chunk of QK^T -> online softmax -> PV for one q-tile.
// ---------------------------------------------------------------------------
__device__ __forceinline__ void attn_step(
    const char* cbuf, char* ptw, const int* padfb, const bf16x8* aq,
    bool iskb, int j0, int s0, int w, int li, int lg4,
    float* m_, float* l_, f32x4* acc) {
  f32x4 cc[4];
  __builtin_amdgcn_s_setprio(1);
#pragma unroll
  for (int cb = 0; cb < 4; ++cb) {
    bf16x8 b0 = *(const bf16x8*)(cbuf + swz(cb * 16 + li, lg4));
    bf16x8 b1 = *(const bf16x8*)(cbuf + swz(cb * 16 + li, 4 + lg4));
    f32x4 z = {};
    z = __builtin_amdgcn_mfma_f32_16x16x32_bf16(aq[0], b0, z, 0, 0, 0);
    z = __builtin_amdgcn_mfma_f32_16x16x32_bf16(aq[1], b1, z, 0, 0, 0);
    cc[cb] = z;
  }
  __builtin_amdgcn_s_setprio(0);

  float lgv[4][4];
#pragma unroll
  for (int cb = 0; cb < 4; ++cb)
#pragma unroll
    for (int j = 0; j < 4; ++j) {
      float v = SCALE * cc[cb][j];
      if (iskb) {
        v += C0F + (padfb[w * 16 + lg4 * 4 + j] ? PADF : 0.f);
      } else {
        int key = j0 + cb * 16 + li;
        int srow = s0 + w * 16 + lg4 * 4 + j;
        v += (key <= srow) ? 0.f : PADF;
      }
      lgv[cb][j] = v;
    }
#pragma unroll
  for (int j = 0; j < 4; ++j) {
    float rmax = fmaxf(fmaxf(lgv[0][j], lgv[1][j]), fmaxf(lgv[2][j], lgv[3][j]));
#pragma unroll
    for (int off = 8; off; off >>= 1) rmax = fmaxf(rmax, __shfl_xor(rmax, off));
    float mn = fmaxf(m_[j], rmax);
    float fs = __expf(m_[j] - mn);
    float csum = 0.f;
#pragma unroll
    for (int cb = 0; cb < 4; ++cb) {
      float pv = __expf(lgv[cb][j] - mn);
      csum += pv;
      int key = cb * 16 + li;
      int rloc = lg4 * 4 + j;
      *(unsigned short*)(ptw + swz(rloc, key >> 3) + ((key & 7) << 1)) = f2bf(pv);
    }
#pragma unroll
    for (int off = 8; off; off >>= 1) csum += __shfl_xor(csum, off);
    m_[j] = mn;
    l_[j] = l_[j] * fs + csum;
#pragma unroll
    for (int db = 0; db < 4; ++db) acc[db][j] *= fs;
  }

  bf16x8 pa0 = *(const bf16x8*)(ptw + swz(li, lg4));
  bf16x8 pa1 = *(const bf16x8*)(ptw + swz(li, 4 + lg4));
  __builtin_amdgcn_s_setprio(1);
#pragma unroll
  for (int db = 0; db < 4; ++db) {
    bf16x8 bv0 = *(const bf16x8*)(cbuf + 8192 + swz(db * 16 + li, lg4));
    bf16x8 bv1 = *(const bf16x8*)(cbuf + 8192 + swz(db * 16 + li, 4 + lg4));
    acc[db] = __builtin_amdgcn_mfma_f32_16x16x32_bf16(pa0, bv0, acc[db], 0, 0, 0);
    acc[db] = __builtin_amdgcn_mfma_f32_16x16x32_bf16(pa1, bv1, acc[db], 0, 0, 0);
  }
  __builtin_amdgcn_s_setprio(0);
}

// ---------------------------------------------------------------------------
// MFMA fused attention v5 (unchanged): diagonal pairing + async reg-staged
// prefetch + double-buffered K/V LDS (1 barrier/chunk).
// ---------------------------------------------------------------------------
__global__ __launch_bounds__(256) void attn_mfma(
    const unsigned short* __restrict__ qbf,    // [B*S][2048] roped bf16
    const unsigned short* __restrict__ q2bf,   // [B*S][2048] bf16
    const unsigned short* __restrict__ kbf,    // [B*S][512] roped bf16
    const unsigned short* __restrict__ vTb,    // [B][NKV][64][S] bf16
    const unsigned short* __restrict__ kbkh,   // [128][2048] bf16
    const unsigned short* __restrict__ kbvgT,  // [B][NH][64][128] bf16
    const int* __restrict__ padflag,           // [B*S]
    unsigned short* __restrict__ attnbf,       // [B*S][2048] bf16
    int B, int S) {
  const int nst = S >> 6;
  const int npair = (nst + 1) >> 1;
  const int p = blockIdx.x % npair;
  const int h = (blockIdx.x / npair) % NH;
  const int b = blockIdx.x / (npair * NH);
  const int stA = p, stB = nst - 1 - p;
  const bool hasB = (stB != stA);
  const int s0A = stA * 64, s0B = stB * 64;
  const int g = h / (NH / NKV);

  __shared__ unsigned short smem[2][8192];
  __shared__ unsigned short pt[4][1024];
  __shared__ int padf[128];

  const int t = threadIdx.x;
  const int w = t >> 6;
  const int li = t & 15;
  const int lg4 = (t & 63) >> 4;

  const int nch = 2 + stB + 1;

  bf16x8 st[4];
  load_chunk(0, t, b, h, g, S, kbf, vTb, kbkh, kbvgT, st);

  bf16x8 aq0A[2], aq2A[2], aq0B[2], aq2B[2];
  {
    size_t rowA = (size_t)(b * S + s0A + w * 16 + li) * (NH * HD);
    size_t rowB = (size_t)(b * S + s0B + w * 16 + li) * (NH * HD);
#pragma unroll
    for (int kc = 0; kc < 2; ++kc) {
      size_t o = h * 64 + kc * 32 + lg4 * 8;
      aq0A[kc] = *(const bf16x8*)(qbf + rowA + o);
      aq2A[kc] = *(const bf16x8*)(q2bf + rowA + o);
      aq0B[kc] = *(const bf16x8*)(qbf + rowB + o);
      aq2B[kc] = *(const bf16x8*)(q2bf + rowB + o);
    }
  }
  if (t < 64) padf[t] = padflag[b * S + s0A + t];
  else if (t < 128) padf[t] = padflag[b * S + s0B + (t - 64)];

#pragma unroll
  for (int it = 0; it < 4; ++it) {
    int slot = it * 256 + t;
    int tile = slot >> 9, row = (slot >> 3) & 63, ck = slot & 7;
    *(bf16x8*)((char*)smem[0] + tile * 8192 + swz(row, ck)) = st[it];
  }
  load_chunk(1, t, b, h, g, S, kbf, vTb, kbkh, kbvgT, st);
  __syncthreads();

  float mA[4] = {-3.4e38f, -3.4e38f, -3.4e38f, -3.4e38f};
  float mB[4] = {-3.4e38f, -3.4e38f, -3.4e38f, -3.4e38f};
  float lA[4] = {}, lB[4] = {};
  f32x4 accA[4] = {}, accB[4] = {};

  for (int ch = 0; ch < nch; ++ch) {
    const bool iskb = ch < 2;
    const int j0 = iskb ? ch * 64 : (ch - 2) * 64;
    if (ch + 1 < nch) {
      char* nb = (char*)smem[(ch + 1) & 1];
#pragma unroll
      for (int it = 0; it < 4; ++it) {
        int slot = it * 256 + t;
        int tile = slot >> 9, row = (slot >> 3) & 63, ck = slot & 7;
        *(bf16x8*)(nb + tile * 8192 + swz(row, ck)) = st[it];
      }
      if (ch + 2 < nch)
        load_chunk(ch + 2, t, b, h, g, S, kbf, vTb, kbkh, kbvgT, st);
    }
    const char* cb = (const char*)smem[ch & 1];
    if (iskb || (ch - 2) <= stA)
      attn_step(cb, (char*)pt[w], padf, iskb ? aq2A : aq0A,
                iskb, j0, s0A, w, li, lg4, mA, lA, accA);
    if (hasB)
      attn_step(cb, (char*)pt[w], padf + 64, iskb ? aq2B : aq0B,
                iskb, j0, s0B, w, li, lg4, mB, lB, accB);
    __syncthreads();
  }

#pragma unroll
  for (int j = 0; j < 4; ++j) {
    float inv = 1.f / lA[j];
    size_t o = (size_t)(b * S + s0A + w * 16 + lg4 * 4 + j) * (NH * HD) + h * 64 + li;
#pragma unroll
    for (int db = 0; db < 4; ++db) attnbf[o + db * 16] = f2bf(accA[db][j] * inv);
  }
  if (hasB) {
#pragma unroll
    for (int j = 0; j < 4; ++j) {
      float inv = 1.f / lB[j];
      size_t o = (size_t)(b * S + s0B + w * 16 + lg4 * 4 + j) * (NH * HD) + h * 64 + li;
#pragma unroll
      for (int db = 0; db < 4; ++db) attnbf[o + db * 16] = f2bf(accB[db][j] * inv);
    }
  }
}

// ---------------------------------------------------------------------------
extern "C" void kernel_launch(void* const* d_in, const int* in_sizes, int n_in,
                              void* d_out, int out_size, void* d_ws, size_t ws_size,
                              hipStream_t stream) {
  const float* hidden = (const float*)d_in[0];
  const float* cosb   = (const float*)d_in[1];
  const float* sinb   = (const float*)d_in[2];
  const float* mask   = (const float*)d_in[3];
  const float* kbk    = (const float*)d_in[4];
  const float* kbv    = (const float*)d_in[5];
  const float* Wq     = (const float*)d_in[6];
  const float* Wq2    = (const float*)d_in[7];
  const float* Wk     = (const float*)d_in[8];
  const float* Wv     = (const float*)d_in[9];
  const float* Wo     = (const float*)d_in[10];
  float* out = (float*)d_out;

  const int H   = in_sizes[6] / (NH * HD);             // 2048
  const int KBL = in_sizes[4] / KBROW;                 // 400
  const long long BSll = (long long)in_sizes[0] / H;
  const int S = (int)((long long)in_sizes[3] / BSll);  // 1024
  const int B = (int)(BSll / S);                       // 2
  const int BS = B * S;
  const int NQ = NH * HD;                              // 2048
  const int NKVD = NKV * HD;                           // 512
  const int NTOT = NQ + NQ + NKVD + NKVD;              // 5120

  float* ws = (float*)d_ws;
  size_t off = 0;
  double* hpart = (double*)(ws + off); off += (size_t)B * HCH * H * 2;
  float* Hsum = ws + off; off += (size_t)B * H;
  float* Qs   = ws + off; off += (size_t)B * NQ;
  float* sc   = ws + off; off += (size_t)B * KBL;
  int* topi   = (int*)(ws + off); off += (size_t)B * TOPK;
  int* padfl  = (int*)(ws + off); off += (size_t)BS;
  unsigned short* hbf    = (unsigned short*)(ws + off); off += (size_t)BS * H / 2;
  unsigned short* wall   = (unsigned short*)(ws + off); off += (size_t)NTOT * H / 2;
  unsigned short* wobf   = (unsigned short*)(ws + off); off += (size_t)H * NQ / 2;
  unsigned short* attnbf = (unsigned short*)(ws + off); off += (size_t)BS * NQ / 2;
  unsigned short* qbf    = (unsigned short*)(ws + off); off += (size_t)BS * NQ / 2;
  unsigned short* q2bf   = (unsigned short*)(ws + off); off += (size_t)BS * NQ / 2;
  unsigned short* kbf    = (unsigned short*)(ws + off); off += (size_t)BS * NKVD / 2;
  unsigned short* vTb    = (unsigned short*)(ws + off); off += (size_t)BS * NKVD / 2;
  unsigned short* kbkh   = (unsigned short*)(ws + off); off += (size_t)128 * NQ / 2;
  unsigned short* kbvgT  = (unsigned short*)(ws + off); off += (size_t)B * NH * HD * TOPK / 2;
  (void)ws_size; (void)n_in; (void)out_size;

  // 0: merged weight f2bf (wall|wobf) + hidden colsum stage 1 + hidden f2bf
  {
    int n1 = NQ * H / 4, n2 = NQ * H / 4;
    int n3 = NKVD * H / 4, n4_ = NKVD * H / 4, n5 = H * NQ / 4;
    int ntot = n1 + n2 + n3 + n4_ + n5;
    int nconv = (ntot + 255) / 256;
    int nh1 = B * HCH * (H / 256);
    conv_hsum1<<<nconv + nh1, 256, 0, stream>>>(
        Wq, Wq2, Wk, Wv, Wo, n1, n2, n3, n4_, n5, nconv, wall,
        hidden, hpart, hbf, B, S, H);
  }

  // 1: fused projections + RoPE + direct V^T (16-wave, 4 waves/SIMD)
  gemm_proj8<<<dim3(NTOT / 256, BS / 256), 1024, 0, stream>>>(
      hbf, wall, cosb, sinb, qbf, q2bf, kbf, vTb, BS, H, S);

  // 2-5: exact fp32 scores path + top-k; merged kbkh + padflag
  hsum2_kernel<<<(B * H + 255) / 256, 256, 0, stream>>>(hpart, Hsum, B, H);
  qs_kernel<<<(B * NQ * 64 + 255) / 256, 256, 0, stream>>>(Hsum, Wq2, Qs, B, H);
  scores_kernel<<<(B * KBL * 64 + 255) / 256, 256, 0, stream>>>(Qs, kbk, sc, B, KBL);
  topk_kernel<<<B, 256, 0, stream>>>(sc, topi, KBL);
  kbkh_padflag<<<256 + (BS * 64 + 255) / 256, 256, 0, stream>>>(
      kbk, kbkh, mask, padfl, BS, S);

  // 6: gathered KB values (needs topi)
  kbvgt_kernel<<<B * NH, 256, 0, stream>>>(kbv, topi, kbvgT, B);

  // 7: fused attention (paired tiles, double-buffered, 1 barrier/chunk)
  {
    int nst = S / 64;
    int npair = (nst + 1) / 2;
    attn_mfma<<<B * NH * npair, 256, 0, stream>>>(
        qbf, q2bf, kbf, vTb, kbkh, kbvgT, padfl, attnbf, B, S);
  }

  // 8-9: output projection, split-K=2 with deterministic atomic accumulation
  hipMemsetAsync(out, 0, (size_t)BS * H * sizeof(float), stream);
  gemm_nt_splitk<<<dim3(H / 128, BS / 128, 2), 256, 0, stream>>>(
      attnbf, wobf, out, BS, H, NQ);
}

// Round 18
// 242.786 us; speedup vs baseline: 1.0593x; 1.0593x over previous
//
#include <hip/hip_runtime.h>
#include <hip/hip_bf16.h>
#include <math.h>

#define NH 32
#define NKV 8
#define HD 64
#define NSLOTS 11
#define TOPK 128
#define KBROW (NSLOTS * NH * HD)   // 22528
#define PADF (-3.3895313892515355e+38f)
#define C0F  (-0.24686007793152578f)   // -ln(128)+ln(100)
#define SCALE 0.125f
#define HCH 32                         // S-chunks for hierarchical column sum

typedef __attribute__((ext_vector_type(8))) __bf16 bf16x8;
typedef __attribute__((ext_vector_type(8))) unsigned short u16x8;
typedef __attribute__((ext_vector_type(4))) float f32x4;

#define GLDS16(gp, lp)                                                        \
  __builtin_amdgcn_global_load_lds(                                           \
      (__attribute__((address_space(1))) void*)(gp),                          \
      (__attribute__((address_space(3))) void*)(lp), 16, 0, 0)

__device__ __forceinline__ unsigned short f2bf(float f) {
  unsigned int u = __float_as_uint(f);
  u = (u + 0x7fffu + ((u >> 16) & 1u)) >> 16;
  return (unsigned short)u;
}

// byte offset into a 64-col bf16 tile (128 B/row) with XOR chunk swizzle
__device__ __forceinline__ int swz(int row, int chunk) {
  return row * 128 + ((chunk ^ (row & 7)) << 4);
}

// ---------------------------------------------------------------------------
// Merged: (a) fp32->bf16 of 5 weight sources into wall|wobf (flat copy),
// (b) hidden column-sum stage 1 + fused hidden f2bf.
// ---------------------------------------------------------------------------
__global__ __launch_bounds__(256) void conv_hsum1(
    const float* __restrict__ s0, const float* __restrict__ s1,
    const float* __restrict__ s2, const float* __restrict__ s3,
    const float* __restrict__ s4,
    int n0, int n1, int n2, int n3, int n4_, int nconv,
    unsigned short* __restrict__ wout,
    const float* __restrict__ hidden, double* __restrict__ part,
    unsigned short* __restrict__ hbf, int B, int S, int H) {
  if ((int)blockIdx.x < nconv) {
    int i = blockIdx.x * 256 + threadIdx.x;
    int j = i;
    const float* src;
    if (j < n0) src = s0;
    else { j -= n0; if (j < n1) src = s1;
    else { j -= n1; if (j < n2) src = s2;
    else { j -= n2; if (j < n3) src = s3;
    else { j -= n3; if (j >= n4_) return; src = s4; }}}}
    float4 v = ((const float4*)src)[j];
    ushort4 o = {f2bf(v.x), f2bf(v.y), f2bf(v.z), f2bf(v.w)};
    ((ushort4*)wout)[i] = o;
  } else {
    int bid = blockIdx.x - nconv;
    const int nhb = H >> 8;
    int hb = bid % nhb;
    int ch = (bid / nhb) % HCH;
    int b  = bid / (nhb * HCH);
    int c  = hb * 256 + threadIdx.x;
    int rows = S / HCH;
    size_t base = ((size_t)b * S + (size_t)ch * rows) * H + c;
    const float* p = hidden + base;
    double acc = 0.0;
    for (int s = 0; s < rows; ++s) {
      float v = p[(size_t)s * H];
      acc += (double)v;
      hbf[base + (size_t)s * H] = f2bf(v);
    }
    part[((size_t)b * HCH + ch) * H + c] = acc;
  }
}

// ---------------------------------------------------------------------------
// bf16 MFMA GEMM, split-K=2 (m97 structure) — Wo projection, plain stores.
// ---------------------------------------------------------------------------
__global__ __launch_bounds__(256) void gemm_nt_splitk(
    const unsigned short* __restrict__ A, const unsigned short* __restrict__ B,
    float* __restrict__ C0, float* __restrict__ C1, int M, int N, int K) {
  __shared__ unsigned short ldsA[128 * 32];
  __shared__ unsigned short ldsB[128 * 32];
  const int t = threadIdx.x;
  const int l = t & 63, w = t >> 6;
  const int wr = w >> 1, wc = w & 1;
  const int lr = l & 15;
  const int kb = (l >> 4) * 16;
  const int bm = blockIdx.y * 128, bn = blockIdx.x * 128;
  float* C = blockIdx.z ? C1 : C0;
  const int k0base = blockIdx.z * (K >> 1);
  const int kend = k0base + (K >> 1);

  f32x4 acc[4][4] = {};

  for (int k0 = k0base; k0 < kend; k0 += 32) {
    __syncthreads();
#pragma unroll
    for (int it = 0; it < 2; ++it) {
      int s = it * 256 + t;
      int row = s >> 2, cs = (s & 3) * 8;
      GLDS16(A + (size_t)(bm + row) * K + k0 + cs,
             (char*)ldsA + (it * 4 + w) * 1024);
      GLDS16(B + (size_t)(bn + row) * K + k0 + cs,
             (char*)ldsB + (it * 4 + w) * 1024);
    }
    __syncthreads();

    bf16x8 a[4], b[4];
#pragma unroll
    for (int m = 0; m < 4; ++m)
      a[m] = *(const bf16x8*)((const char*)ldsA +
                              (wr * 64 + m * 16 + lr) * 64 + kb);
#pragma unroll
    for (int n = 0; n < 4; ++n)
      b[n] = *(const bf16x8*)((const char*)ldsB +
                              (wc * 64 + n * 16 + lr) * 64 + kb);
#pragma unroll
    for (int m = 0; m < 4; ++m)
#pragma unroll
      for (int n = 0; n < 4; ++n)
        acc[m][n] =
            __builtin_amdgcn_mfma_f32_16x16x32_bf16(a[m], b[n], acc[m][n], 0, 0, 0);
  }

#pragma unroll
  for (int m = 0; m < 4; ++m)
#pragma unroll
    for (int n = 0; n < 4; ++n) {
      int rbase = bm + wr * 64 + m * 16 + ((l >> 4) << 2);
      int cbase = bn + wc * 64 + n * 16 + lr;
#pragma unroll
      for (int j = 0; j < 4; ++j)
        C[(size_t)(rbase + j) * N + cbase] = acc[m][n][j];
    }
}

// ---------------------------------------------------------------------------
// out = a + b (float4 units)
// ---------------------------------------------------------------------------
__global__ void add2_kernel(const float* __restrict__ a,
                            const float* __restrict__ b,
                            float* __restrict__ o, int n4) {
  int i = blockIdx.x * blockDim.x + threadIdx.x;
  if (i >= n4) return;
  float4 x = ((const float4*)a)[i], y = ((const float4*)b)[i];
  ((float4*)o)[i] = make_float4(x.x + y.x, x.y + y.y, x.z + y.z, x.w + y.w);
}

// ---------------------------------------------------------------------------
// 16-wave 256x256 deep-pipelined projection GEMM + RoPE epilogue + direct
// V^T. (v6, unchanged from R16.)
// ---------------------------------------------------------------------------
__global__ __launch_bounds__(1024) void gemm_proj8(
    const unsigned short* __restrict__ A,      // hbf [M][K]
    const unsigned short* __restrict__ Wall,   // [5120][K]
    const float* __restrict__ cosb, const float* __restrict__ sinb,
    unsigned short* __restrict__ qbf, unsigned short* __restrict__ q2bf,
    unsigned short* __restrict__ kbf, unsigned short* __restrict__ vTb,
    int M, int K, int S) {
  __shared__ char lds[131072];  // 2 buffers x (A 32KB | B 32KB)
  const int t = threadIdx.x;
  const int w = t >> 6;                 // 0..15
  const int wm = w >> 2, wn = w & 3;    // 4M x 4N
  const int l = t & 63;
  const int li = l & 15, lg4 = l >> 4;
  const int bm = blockIdx.y * 256, bn = blockIdx.x * 256;
  const int NK = K >> 6;

  f32x4 acc[4][4] = {};

#define STAGE_UNIT(kt1, nb, u)                                                \
  {                                                                           \
    const int slice_ = (u) >> 1;                                              \
    const unsigned short* mat_ = ((u) & 1) ? Wall : A;                        \
    const int tb_ = ((u) & 1) ? bn : bm;                                      \
    char* base_ = lds + (nb) * 65536 + (((u) & 1) ? 32768 : 0) +              \
                  slice_ * 16384;                                             \
    int row_ = t >> 2, cc_ = t & 3;                                           \
    int chunk_ = cc_ ^ ((row_ >> 1) & 3);                                     \
    GLDS16(mat_ + (size_t)(tb_ + row_) * K + (kt1) * 64 + slice_ * 32 +       \
               chunk_ * 8,                                                    \
           base_ + w * 1024);                                                 \
  }

  STAGE_UNIT(0, 0, 0); STAGE_UNIT(0, 0, 1);
  STAGE_UNIT(0, 0, 2); STAGE_UNIT(0, 0, 3);
  asm volatile("s_waitcnt vmcnt(2)" ::: "memory");
  asm volatile("s_barrier" ::: "memory");

  for (int kt = 0; kt < NK; ++kt) {
    const int cur = kt & 1;
    const bool stg = (kt + 1 < NK);
    char* curA = lds + cur * 65536;
    char* curB = curA + 32768;
#pragma unroll
    for (int kk = 0; kk < 2; ++kk) {
      bf16x8 bfr[4], af[4];
#pragma unroll
      for (int n = 0; n < 4; ++n) {
        int row = wn * 64 + n * 16 + li;
        bfr[n] = *(const bf16x8*)(curB + kk * 16384 + row * 64 +
                                  ((lg4 ^ ((row >> 1) & 3)) << 4));
      }
#pragma unroll
      for (int mi = 0; mi < 4; ++mi) {
        int row = wm * 64 + mi * 16 + li;
        af[mi] = *(const bf16x8*)(curA + kk * 16384 + row * 64 +
                                  ((lg4 ^ ((row >> 1) & 3)) << 4));
      }
      if (stg) {
        STAGE_UNIT(kt + 1, cur ^ 1, kk * 2)
        STAGE_UNIT(kt + 1, cur ^ 1, kk * 2 + 1)
      }
#pragma unroll
      for (int mi = 0; mi < 4; ++mi)
#pragma unroll
        for (int n = 0; n < 4; ++n)
          acc[mi][n] = __builtin_amdgcn_mfma_f32_16x16x32_bf16(
              af[mi], bfr[n], acc[mi][n], 0, 0, 0);
      if (kk == 0) {
        if (kt == NK - 1) asm volatile("s_waitcnt vmcnt(0)" ::: "memory");
        else              asm volatile("s_waitcnt vmcnt(2)" ::: "memory");
        asm volatile("s_barrier" ::: "memory");
      } else {
        if (stg) {
          asm volatile("s_waitcnt vmcnt(2)" ::: "memory");
          asm volatile("s_barrier" ::: "memory");
        }
      }
    }
  }
#undef STAGE_UNIT

  const int seg = bn;  // block-uniform
#pragma unroll
  for (int m = 0; m < 4; ++m) {
    const int row0 = bm + wm * 64 + m * 16 + lg4 * 4;
    if (seg < 2048 || (seg >= 4096 && seg < 4608)) {
      const bool isq = seg < 2048;
#pragma unroll
      for (int j = 0; j < 4; ++j) {
        int row = row0 + j;
        const float* cr = cosb + (size_t)row * 64;
        const float* sr = sinb + (size_t)row * 64;
        float c0 = cr[li], c1 = cr[16 + li], c2 = cr[32 + li], c3 = cr[48 + li];
        float sa = sr[li], sb = sr[16 + li], sc_ = sr[32 + li], sd = sr[48 + li];
        float x0 = acc[m][0][j], x1 = acc[m][1][j];
        float x2 = acc[m][2][j], x3 = acc[m][3][j];
        float y0 = x0 * c0 - x2 * sa;
        float y1 = x1 * c1 - x3 * sb;
        float y2 = x2 * c2 + x0 * sc_;
        float y3 = x3 * c3 + x1 * sd;
        if (isq) {
          size_t ro = (size_t)row * 2048 + bn + wn * 64 + li;
          qbf[ro] = f2bf(y0); qbf[ro + 16] = f2bf(y1);
          qbf[ro + 32] = f2bf(y2); qbf[ro + 48] = f2bf(y3);
        } else {
          size_t ro = (size_t)row * 512 + (bn - 4096) + wn * 64 + li;
          kbf[ro] = f2bf(y0); kbf[ro + 16] = f2bf(y1);
          kbf[ro + 32] = f2bf(y2); kbf[ro + 48] = f2bf(y3);
        }
      }
    } else if (seg < 4096) {  // q2 -> bf16
#pragma unroll
      for (int n = 0; n < 4; ++n) {
        int col = bn - 2048 + wn * 64 + n * 16 + li;
#pragma unroll
        for (int j = 0; j < 4; ++j)
          q2bf[(size_t)(row0 + j) * 2048 + col] = f2bf(acc[m][n][j]);
      }
    } else {  // v -> vT bf16 direct (j=0..3 consecutive s)
      int b_ = row0 / S, s = row0 % S;
#pragma unroll
      for (int n = 0; n < 4; ++n) {
        int col = (bn - 4608) + wn * 64 + n * 16 + li;
        int gg = col >> 6, d = col & 63;
        ushort4 o = {f2bf(acc[m][n][0]), f2bf(acc[m][n][1]),
                     f2bf(acc[m][n][2]), f2bf(acc[m][n][3])};
        *(ushort4*)&vTb[(((size_t)b_ * NKV + gg) * 64 + d) * S + s] = o;
      }
    }
  }
}

// ---------------------------------------------------------------------------
// Merged: (a) KB key slice bf16 (blocks [0,256)), (b) padflag (blocks 256+).
// ---------------------------------------------------------------------------
__global__ __launch_bounds__(256) void kbkh_padflag(
    const float* __restrict__ kbk, unsigned short* __restrict__ kout,
    const float* __restrict__ mask, int* __restrict__ flags, int BS, int S) {
  if (blockIdx.x < 256) {
    int i = blockIdx.x * 256 + threadIdx.x;
    int j = i >> 9, c4 = (i & 511) * 4;
    float4 v = *(const float4*)&kbk[(size_t)j * KBROW + c4];
    ushort4 o = {f2bf(v.x), f2bf(v.y), f2bf(v.z), f2bf(v.w)};
    *(ushort4*)&kout[(size_t)j * 2048 + c4] = o;
  } else {
    int w = (((int)blockIdx.x - 256) * 256 + (int)threadIdx.x) >> 6;
    int lane = threadIdx.x & 63;
    if (w >= BS) return;
    const float* row = mask + (size_t)w * S;
    bool ok = true;
    for (int j = lane; j < S; j += 64) ok = ok && (row[j] < 0.f);
    int allv = __all(ok ? 1 : 0);
    if (lane == 0) flags[w] = allv;
  }
}

// ---------------------------------------------------------------------------
// Gathered + transposed KB values -> [B][NH][64][128] bf16.
// ---------------------------------------------------------------------------
__global__ __launch_bounds__(256) void kbvgt_kernel(
    const float* __restrict__ kbv, const int* __restrict__ topi,
    unsigned short* __restrict__ kbvgT, int B) {
  int h = blockIdx.x % NH, b = blockIdx.x / NH;
  __shared__ unsigned short gt[128][72];
  __shared__ int lidx[TOPK];
  int t = threadIdx.x;
  if (t < TOPK) lidx[t] = topi[b * TOPK + t];
  __syncthreads();
#pragma unroll
  for (int it = 0; it < 8; ++it) {
    int slot = it * 256 + t;
    int j = slot >> 4, d4 = (slot & 15) * 4;
    float4 v = *(const float4*)&kbv[(size_t)lidx[j] * KBROW + h * 64 + d4];
    gt[j][d4] = f2bf(v.x); gt[j][d4 + 1] = f2bf(v.y);
    gt[j][d4 + 2] = f2bf(v.z); gt[j][d4 + 3] = f2bf(v.w);
  }
  __syncthreads();
#pragma unroll
  for (int it = 0; it < 4; ++it) {
    int slot = it * 256 + t;
    int d = slot >> 4, j8 = (slot & 15) * 8;
    u16x8 o;
#pragma unroll
    for (int j = 0; j < 8; ++j) o[j] = gt[j8 + j][d];
    *(u16x8*)&kbvgT[(((size_t)b * NH + h) * 64 + d) * 128 + j8] = o;
  }
}

// ---------------------------------------------------------------------------
// Column-sum stage 2: Hsum[b][c] = sum_ch part[b][ch][c] (f64, fixed order).
// ---------------------------------------------------------------------------
__global__ void hsum2_kernel(const double* __restrict__ part,
                             float* __restrict__ Hsum, int B, int H) {
  int idx = blockIdx.x * blockDim.x + threadIdx.x;
  if (idx >= B * H) return;
  int b = idx / H, c = idx % H;
  const double* p = part + (size_t)b * HCH * H + c;
  double acc = 0.0;
#pragma unroll
  for (int ch = 0; ch < HCH; ++ch) acc += p[(size_t)ch * H];
  Hsum[idx] = (float)acc;
}

// ---------------------------------------------------------------------------
// Qs[b][c] = sum_k Hsum[b][k] * Wq2[c][k]  (fp32 inputs, f64 accum).
// ---------------------------------------------------------------------------
__global__ void qs_kernel(const float* __restrict__ Hsum,
                          const float* __restrict__ Wq2,
                          float* __restrict__ Qs, int B, int H) {
  int task = (blockIdx.x * blockDim.x + threadIdx.x) >> 6;
  int lane = threadIdx.x & 63;
  if (task >= B * NH * HD) return;
  int b = task / (NH * HD), c = task % (NH * HD);
  const float* hs = Hsum + (size_t)b * H;
  const float* wr = Wq2 + (size_t)c * H;
  double acc = 0.0;
  for (int k = lane; k < H; k += 64) acc += (double)hs[k] * (double)wr[k];
#pragma unroll
  for (int off = 32; off; off >>= 1) acc += __shfl_xor(acc, off);
  if (lane == 0) Qs[task] = (float)acc;
}

// ---------------------------------------------------------------------------
// scores[b][l] = 0.125 * dot(Qs[b,:], kb_keys[l, 0:2048]) (f64 acc)
// ---------------------------------------------------------------------------
__global__ void scores_kernel(const float* __restrict__ Qs,
                              const float* __restrict__ kbk,
                              float* __restrict__ scores, int B, int KBL) {
  int task = (blockIdx.x * blockDim.x + threadIdx.x) >> 6;
  int lane = threadIdx.x & 63;
  if (task >= B * KBL) return;
  int b = task / KBL, l = task % KBL;
  const float* kr = kbk + (size_t)l * KBROW;
  const float* qd = Qs + (size_t)b * NH * HD;
  double acc = 0.0;
  for (int c = lane; c < NH * HD; c += 64) acc += (double)qd[c] * (double)kr[c];
#pragma unroll
  for (int off = 32; off; off >>= 1) acc += __shfl_xor(acc, off);
  if (lane == 0) scores[task] = (float)(0.125 * acc);
}

// ---------------------------------------------------------------------------
// Top-K by rank-counting (stable descending == lax.top_k).
// ---------------------------------------------------------------------------
__global__ __launch_bounds__(256) void topk_kernel(
    const float* __restrict__ scores, int* __restrict__ top_idx, int KBL) {
  __shared__ float ls[512];
  int b = blockIdx.x, t = threadIdx.x;
  for (int i = t; i < KBL; i += 256) ls[i] = scores[(size_t)b * KBL + i];
  __syncthreads();
  for (int l = t; l < KBL; l += 256) {
    float sl = ls[l];
    int rank = 0;
    for (int j = 0; j < KBL; ++j) {
      float sj = ls[j];
      rank += (sj > sl || (sj == sl && j < l)) ? 1 : 0;
    }
    if (rank < TOPK) top_idx[b * TOPK + rank] = l;
  }
}

// ---------------------------------------------------------------------------
// Load one K/V chunk's staged data into registers (4 x bf16x8 per thread).
// ---------------------------------------------------------------------------
__device__ __forceinline__ void load_chunk(
    int ch, int t, int b, int h, int g, int S,
    const unsigned short* __restrict__ kbf, const unsigned short* __restrict__ vTb,
    const unsigned short* __restrict__ kbkh, const unsigned short* __restrict__ kbvgT,
    bf16x8* st) {
  bool iskb = ch < 2;
  int j0 = iskb ? ch * 64 : (ch - 2) * 64;
#pragma unroll
  for (int it = 0; it < 4; ++it) {
    int slot = it * 256 + t;
    int tile = slot >> 9, row = (slot >> 3) & 63, ck = slot & 7;
    const unsigned short* src;
    if (tile == 0)
      src = iskb ? kbkh + (size_t)(j0 + row) * 2048 + h * 64 + ck * 8
                 : kbf + (size_t)(b * S + j0 + row) * 512 + g * 64 + ck * 8;
    else
      src = iskb ? kbvgT + (((size_t)b * NH + h) * 64 + row) * 128 + j0 + ck * 8
                 : vTb + (((size_t)b * NKV + g) * 64 + row) * (size_t)S + j0 + ck * 8;
    st[it] = *(const bf16x8*)src;
  }
}

// ---------------------------------------------------------------------------
// One chunk of QK^T -> online softmax -> PV for one q-tile.
// ---------------------------------------------------------------------------
__device__ __forceinline__ void attn_step(
    const char* cbuf, char* ptw, const int* padfb, const bf16x8* aq,
    bool iskb, int j0, int s0, int w, int li, int lg4,
    float* m_, float* l_, f32x4* acc) {
  f32x4 cc[4];
  __builtin_amdgcn_s_setprio(1);
#pragma unroll
  for (int cb = 0; cb < 4; ++cb) {
    bf16x8 b0 = *(const bf16x8*)(cbuf + swz(cb * 16 + li, lg4));
    bf16x8 b1 = *(const bf16x8*)(cbuf + swz(cb * 16 + li, 4 + lg4));
    f32x4 z = {};
    z = __builtin_amdgcn_mfma_f32_16x16x32_bf16(aq[0], b0, z, 0, 0, 0);
    z = __builtin_amdgcn_mfma_f32_16x16x32_bf16(aq[1], b1, z, 0, 0, 0);
    cc[cb] = z;
  }
  __builtin_amdgcn_s_setprio(0);

  float lgv[4][4];
#pragma unroll
  for (int cb = 0; cb < 4; ++cb)
#pragma unroll
    for (int j = 0; j < 4; ++j) {
      float v = SCALE * cc[cb][j];
      if (iskb) {
        v += C0F + (padfb[w * 16 + lg4 * 4 + j] ? PADF : 0.f);
      } else {
        int key = j0 + cb * 16 + li;
        int srow = s0 + w * 16 + lg4 * 4 + j;
        v += (key <= srow) ? 0.f : PADF;
      }
      lgv[cb][j] = v;
    }
#pragma unroll
  for (int j = 0; j < 4; ++j) {
    float rmax = fmaxf(fmaxf(lgv[0][j], lgv[1][j]), fmaxf(lgv[2][j], lgv[3][j]));
#pragma unroll
    for (int off = 8; off; off >>= 1) rmax = fmaxf(rmax, __shfl_xor(rmax, off));
    float mn = fmaxf(m_[j], rmax);
    float fs = __expf(m_[j] - mn);
    float csum = 0.f;
#pragma unroll
    for (int cb = 0; cb < 4; ++cb) {
      float pv = __expf(lgv[cb][j] - mn);
      csum += pv;
      int key = cb * 16 + li;
      int rloc = lg4 * 4 + j;
      *(unsigned short*)(ptw + swz(rloc, key >> 3) + ((key & 7) << 1)) = f2bf(pv);
    }
#pragma unroll
    for (int off = 8; off; off >>= 1) csum += __shfl_xor(csum, off);
    m_[j] = mn;
    l_[j] = l_[j] * fs + csum;
#pragma unroll
    for (int db = 0; db < 4; ++db) acc[db][j] *= fs;
  }

  bf16x8 pa0 = *(const bf16x8*)(ptw + swz(li, lg4));
  bf16x8 pa1 = *(const bf16x8*)(ptw + swz(li, 4 + lg4));
  __builtin_amdgcn_s_setprio(1);
#pragma unroll
  for (int db = 0; db < 4; ++db) {
    bf16x8 bv0 = *(const bf16x8*)(cbuf + 8192 + swz(db * 16 + li, lg4));
    bf16x8 bv1 = *(const bf16x8*)(cbuf + 8192 + swz(db * 16 + li, 4 + lg4));
    acc[db] = __builtin_amdgcn_mfma_f32_16x16x32_bf16(pa0, bv0, acc[db], 0, 0, 0);
    acc[db] = __builtin_amdgcn_mfma_f32_16x16x32_bf16(pa1, bv1, acc[db], 0, 0, 0);
  }
  __builtin_amdgcn_s_setprio(0);
}

// ---------------------------------------------------------------------------
// MFMA fused attention v5 (unchanged): diagonal pairing + async reg-staged
// prefetch + double-buffered K/V LDS (1 barrier/chunk).
// ---------------------------------------------------------------------------
__global__ __launch_bounds__(256) void attn_mfma(
    const unsigned short* __restrict__ qbf,    // [B*S][2048] roped bf16
    const unsigned short* __restrict__ q2bf,   // [B*S][2048] bf16
    const unsigned short* __restrict__ kbf,    // [B*S][512] roped bf16
    const unsigned short* __restrict__ vTb,    // [B][NKV][64][S] bf16
    const unsigned short* __restrict__ kbkh,   // [128][2048] bf16
    const unsigned short* __restrict__ kbvgT,  // [B][NH][64][128] bf16
    const int* __restrict__ padflag,           // [B*S]
    unsigned short* __restrict__ attnbf,       // [B*S][2048] bf16
    int B, int S) {
  const int nst = S >> 6;
  const int npair = (nst + 1) >> 1;
  const int p = blockIdx.x % npair;
  const int h = (blockIdx.x / npair) % NH;
  const int b = blockIdx.x / (npair * NH);
  const int stA = p, stB = nst - 1 - p;
  const bool hasB = (stB != stA);
  const int s0A = stA * 64, s0B = stB * 64;
  const int g = h / (NH / NKV);

  __shared__ unsigned short smem[2][8192];
  __shared__ unsigned short pt[4][1024];
  __shared__ int padf[128];

  const int t = threadIdx.x;
  const int w = t >> 6;
  const int li = t & 15;
  const int lg4 = (t & 63) >> 4;

  const int nch = 2 + stB + 1;

  bf16x8 st[4];
  load_chunk(0, t, b, h, g, S, kbf, vTb, kbkh, kbvgT, st);

  bf16x8 aq0A[2], aq2A[2], aq0B[2], aq2B[2];
  {
    size_t rowA = (size_t)(b * S + s0A + w * 16 + li) * (NH * HD);
    size_t rowB = (size_t)(b * S + s0B + w * 16 + li) * (NH * HD);
#pragma unroll
    for (int kc = 0; kc < 2; ++kc) {
      size_t o = h * 64 + kc * 32 + lg4 * 8;
      aq0A[kc] = *(const bf16x8*)(qbf + rowA + o);
      aq2A[kc] = *(const bf16x8*)(q2bf + rowA + o);
      aq0B[kc] = *(const bf16x8*)(qbf + rowB + o);
      aq2B[kc] = *(const bf16x8*)(q2bf + rowB + o);
    }
  }
  if (t < 64) padf[t] = padflag[b * S + s0A + t];
  else if (t < 128) padf[t] = padflag[b * S + s0B + (t - 64)];

#pragma unroll
  for (int it = 0; it < 4; ++it) {
    int slot = it * 256 + t;
    int tile = slot >> 9, row = (slot >> 3) & 63, ck = slot & 7;
    *(bf16x8*)((char*)smem[0] + tile * 8192 + swz(row, ck)) = st[it];
  }
  load_chunk(1, t, b, h, g, S, kbf, vTb, kbkh, kbvgT, st);
  __syncthreads();

  float mA[4] = {-3.4e38f, -3.4e38f, -3.4e38f, -3.4e38f};
  float mB[4] = {-3.4e38f, -3.4e38f, -3.4e38f, -3.4e38f};
  float lA[4] = {}, lB[4] = {};
  f32x4 accA[4] = {}, accB[4] = {};

  for (int ch = 0; ch < nch; ++ch) {
    const bool iskb = ch < 2;
    const int j0 = iskb ? ch * 64 : (ch - 2) * 64;
    if (ch + 1 < nch) {
      char* nb = (char*)smem[(ch + 1) & 1];
#pragma unroll
      for (int it = 0; it < 4; ++it) {
        int slot = it * 256 + t;
        int tile = slot >> 9, row = (slot >> 3) & 63, ck = slot & 7;
        *(bf16x8*)(nb + tile * 8192 + swz(row, ck)) = st[it];
      }
      if (ch + 2 < nch)
        load_chunk(ch + 2, t, b, h, g, S, kbf, vTb, kbkh, kbvgT, st);
    }
    const char* cb = (const char*)smem[ch & 1];
    if (iskb || (ch - 2) <= stA)
      attn_step(cb, (char*)pt[w], padf, iskb ? aq2A : aq0A,
                iskb, j0, s0A, w, li, lg4, mA, lA, accA);
    if (hasB)
      attn_step(cb, (char*)pt[w], padf + 64, iskb ? aq2B : aq0B,
                iskb, j0, s0B, w, li, lg4, mB, lB, accB);
    __syncthreads();
  }

#pragma unroll
  for (int j = 0; j < 4; ++j) {
    float inv = 1.f / lA[j];
    size_t o = (size_t)(b * S + s0A + w * 16 + lg4 * 4 + j) * (NH * HD) + h * 64 + li;
#pragma unroll
    for (int db = 0; db < 4; ++db) attnbf[o + db * 16] = f2bf(accA[db][j] * inv);
  }
  if (hasB) {
#pragma unroll
    for (int j = 0; j < 4; ++j) {
      float inv = 1.f / lB[j];
      size_t o = (size_t)(b * S + s0B + w * 16 + lg4 * 4 + j) * (NH * HD) + h * 64 + li;
#pragma unroll
      for (int db = 0; db < 4; ++db) attnbf[o + db * 16] = f2bf(accB[db][j] * inv);
    }
  }
}

// ---------------------------------------------------------------------------
extern "C" void kernel_launch(void* const* d_in, const int* in_sizes, int n_in,
                              void* d_out, int out_size, void* d_ws, size_t ws_size,
                              hipStream_t stream) {
  const float* hidden = (const float*)d_in[0];
  const float* cosb   = (const float*)d_in[1];
  const float* sinb   = (const float*)d_in[2];
  const float* mask   = (const float*)d_in[3];
  const float* kbk    = (const float*)d_in[4];
  const float* kbv    = (const float*)d_in[5];
  const float* Wq     = (const float*)d_in[6];
  const float* Wq2    = (const float*)d_in[7];
  const float* Wk     = (const float*)d_in[8];
  const float* Wv     = (const float*)d_in[9];
  const float* Wo     = (const float*)d_in[10];
  float* out = (float*)d_out;

  const int H   = in_sizes[6] / (NH * HD);             // 2048
  const int KBL = in_sizes[4] / KBROW;                 // 400
  const long long BSll = (long long)in_sizes[0] / H;
  const int S = (int)((long long)in_sizes[3] / BSll);  // 1024
  const int B = (int)(BSll / S);                       // 2
  const int BS = B * S;
  const int NQ = NH * HD;                              // 2048
  const int NKVD = NKV * HD;                           // 512
  const int NTOT = NQ + NQ + NKVD + NKVD;              // 5120

  float* ws = (float*)d_ws;
  size_t off = 0;
  double* hpart = (double*)(ws + off); off += (size_t)B * HCH * H * 2;
  float* Hsum = ws + off; off += (size_t)B * H;
  float* Qs   = ws + off; off += (size_t)B * NQ;
  float* sc   = ws + off; off += (size_t)B * KBL;
  int* topi   = (int*)(ws + off); off += (size_t)B * TOPK;
  int* padfl  = (int*)(ws + off); off += (size_t)BS;
  unsigned short* hbf    = (unsigned short*)(ws + off); off += (size_t)BS * H / 2;
  unsigned short* wall   = (unsigned short*)(ws + off); off += (size_t)NTOT * H / 2;
  unsigned short* wobf   = (unsigned short*)(ws + off); off += (size_t)H * NQ / 2;
  unsigned short* attnbf = (unsigned short*)(ws + off); off += (size_t)BS * NQ / 2;
  unsigned short* qbf    = (unsigned short*)(ws + off); off += (size_t)BS * NQ / 2;
  unsigned short* q2bf   = (unsigned short*)(ws + off); off += (size_t)BS * NQ / 2;
  unsigned short* kbf    = (unsigned short*)(ws + off); off += (size_t)BS * NKVD / 2;
  unsigned short* vTb    = (unsigned short*)(ws + off); off += (size_t)BS * NKVD / 2;
  unsigned short* kbkh   = (unsigned short*)(ws + off); off += (size_t)128 * NQ / 2;
  unsigned short* kbvgT  = (unsigned short*)(ws + off); off += (size_t)B * NH * HD * TOPK / 2;
  // split-K partials alias dead regions
  float* c0 = (float*)qbf;   // dead after attn_mfma
  float* c1 = (float*)wall;  // dead after gemm_proj8
  (void)ws_size; (void)n_in; (void)out_size;

  // 0: merged weight f2bf (wall|wobf) + hidden colsum stage 1 + hidden f2bf
  {
    int n1 = NQ * H / 4, n2 = NQ * H / 4;
    int n3 = NKVD * H / 4, n4_ = NKVD * H / 4, n5 = H * NQ / 4;
    int ntot = n1 + n2 + n3 + n4_ + n5;
    int nconv = (ntot + 255) / 256;
    int nh1 = B * HCH * (H / 256);
    conv_hsum1<<<nconv + nh1, 256, 0, stream>>>(
        Wq, Wq2, Wk, Wv, Wo, n1, n2, n3, n4_, n5, nconv, wall,
        hidden, hpart, hbf, B, S, H);
  }

  // 1: fused projections + RoPE + direct V^T (16-wave, 4 waves/SIMD)
  gemm_proj8<<<dim3(NTOT / 256, BS / 256), 1024, 0, stream>>>(
      hbf, wall, cosb, sinb, qbf, q2bf, kbf, vTb, BS, H, S);

  // 2-5: exact fp32 scores path + top-k; merged kbkh + padflag
  hsum2_kernel<<<(B * H + 255) / 256, 256, 0, stream>>>(hpart, Hsum, B, H);
  qs_kernel<<<(B * NQ * 64 + 255) / 256, 256, 0, stream>>>(Hsum, Wq2, Qs, B, H);
  scores_kernel<<<(B * KBL * 64 + 255) / 256, 256, 0, stream>>>(Qs, kbk, sc, B, KBL);
  topk_kernel<<<B, 256, 0, stream>>>(sc, topi, KBL);
  kbkh_padflag<<<256 + (BS * 64 + 255) / 256, 256, 0, stream>>>(
      kbk, kbkh, mask, padfl, BS, S);

  // 6: gathered KB values (needs topi)
  kbvgt_kernel<<<B * NH, 256, 0, stream>>>(kbv, topi, kbvgT, B);

  // 7: fused attention (paired tiles, double-buffered, 1 barrier/chunk)
  {
    int nst = S / 64;
    int npair = (nst + 1) / 2;
    attn_mfma<<<B * NH * npair, 256, 0, stream>>>(
        qbf, q2bf, kbf, vTb, kbkh, kbvgT, padfl, attnbf, B, S);
  }

  // 8-9: output projection, split-K=2 + partial add (plain stores)
  gemm_nt_splitk<<<dim3(H / 128, BS / 128, 2), 256, 0, stream>>>(
      attnbf, wobf, c0, c1, BS, H, NQ);
  add2_kernel<<<(BS * H / 4 + 255) / 256, 256, 0, stream>>>(c0, c1, out, BS * H / 4);
}